// Round 3
// baseline (98.663 us; speedup 1.0000x reference)
//
#include <hip/hip_runtime.h>
#include <hip/hip_bf16.h>

typedef float f32x4 __attribute__((ext_vector_type(4)));
typedef short bf16x8 __attribute__((ext_vector_type(8)));
typedef unsigned short u16;

#define CS_BLOCKS 1024    // colsum blocks: 4/CU, 16 waves/CU

// ws layout (bytes) — colsum partials live in d_out (scratch before k_main
// overwrites it; stream-ordered so deterministic), so ws stays small.
#define WS_GNN  0         // 128 f32 = 512 B
#define WS_W1F  512       // 64 frags * 1024 B = 65536
#define WS_W2F  66048     // 128 frags * 1024 B = 131072
#define WS_W3F  197120    // 64 frags * 1024 B = 65536  (end: 262656)

__device__ __forceinline__ u16 f2bf(float f) {
    __hip_bfloat16 h = __float2bfloat16(f);   // single v_cvt_pk_bf16_f32
    return *reinterpret_cast<u16*>(&h);
}

__device__ __forceinline__ bf16x8 pack8(f32x4 a, f32x4 b) {
    union { bf16x8 v; __hip_bfloat162 h[4]; } u;
    u.h[0] = __float22bfloat162_rn(make_float2(a[0], a[1]));
    u.h[1] = __float22bfloat162_rn(make_float2(a[2], a[3]));
    u.h[2] = __float22bfloat162_rn(make_float2(b[0], b[1]));
    u.h[3] = __float22bfloat162_rn(make_float2(b[2], b[3]));
    return u.v;
}

// ---------------------------------------------------------------------------
// Kernel A: blocks 0..CS_BLOCKS-1: per-block column-sum partials of x
//           (16 rows in flight, 2 independent f32x4 accs, 2KB/wave/instr).
//           blocks CS_BLOCKS..+127: repack Wf1/Wf2/Wf3 into MFMA-fragment-
//           ordered bf16 (frag fi = nt*KS+k; lane-major within frag).
// ---------------------------------------------------------------------------
__global__ __launch_bounds__(256) void k_prep(
    const float* __restrict__ x,
    const float* __restrict__ Wf1, const float* __restrict__ Wf2,
    const float* __restrict__ Wf3,
    float* __restrict__ part, u16* __restrict__ w1f, u16* __restrict__ w2f,
    u16* __restrict__ w3f, int n)
{
    int b = blockIdx.x, t = threadIdx.x;
    if (b < CS_BLOCKS) {
        __shared__ float red16[16][128];
        int col8 = t & 15, rowo = t >> 4;       // col8: 32B chunk, rowo: 0..15
        int rpb = (n + CS_BLOCKS - 1) / CS_BLOCKS;
        int start = b * rpb;
        int end = min(start + rpb, n);
        f32x4 a0 = {0.f,0.f,0.f,0.f}, a1 = {0.f,0.f,0.f,0.f};
        #pragma unroll 2
        for (int r = start + rowo; r < end; r += 16) {
            const f32x4* p = (const f32x4*)(x + (long)r * 128 + col8 * 8);
            a0 += p[0]; a1 += p[1];
        }
        *(f32x4*)&red16[rowo][col8 * 8]     = a0;
        *(f32x4*)&red16[rowo][col8 * 8 + 4] = a1;
        __syncthreads();
        if (t < 128) {
            float s = 0.f;
            #pragma unroll
            for (int i = 0; i < 16; ++i) s += red16[i][t];
            part[b * 128 + t] = s;
        }
    } else {
        int e0 = ((b - CS_BLOCKS) * 256 + t) * 4; // 131072 elems total
        #pragma unroll
        for (int i = 0; i < 4; ++i) {
            int e = e0 + i;
            u16* dst; const float* src; int KS, NW;
            if (e < 32768)      { dst = w1f; src = Wf1; KS = 4; NW = 256; }
            else if (e < 98304) { dst = w2f; src = Wf2; KS = 8; NW = 256; e -= 32768; }
            else                { dst = w3f; src = Wf3; KS = 8; NW = 128; e -= 98304; }
            int fi = e >> 9, within = e & 511;
            int lane = within >> 3, j = within & 7;
            int nt = fi / KS, k = fi - nt * KS;
            int nn = nt * 16 + (lane & 15);
            int kk = k * 32 + ((lane >> 4) & 3) * 8 + j;
            dst[fi * 512 + within] = f2bf(src[kk * NW + nn]);
        }
    }
}

// ---------------------------------------------------------------------------
// Kernel B: reduce colsum partials -> colmean, run the tiny GCN chain in f32.
// ---------------------------------------------------------------------------
__global__ __launch_bounds__(256) void k_gnn(
    const float* __restrict__ part,
    const float* __restrict__ Wc1, const float* __restrict__ bc1,
    const float* __restrict__ Wc2, const float* __restrict__ bc2,
    const float* __restrict__ g1,  const float* __restrict__ be1,
    const float* __restrict__ g2,  const float* __restrict__ be2,
    float* __restrict__ gnn, int n)
{
    int t = threadIdx.x;
    __shared__ float cm[128];
    __shared__ float hv[256];
    __shared__ float red[256];
    __shared__ float red16[16][128];

    {   // vectorized partial reduce: CS_BLOCKS partials of 128 cols
        int col8 = t & 15, rowo = t >> 4;
        f32x4 a0 = {0.f,0.f,0.f,0.f}, a1 = {0.f,0.f,0.f,0.f};
        for (int p = rowo; p < CS_BLOCKS; p += 16) {
            const f32x4* q = (const f32x4*)(part + p * 128 + col8 * 8);
            a0 += q[0]; a1 += q[1];
        }
        *(f32x4*)&red16[rowo][col8 * 8]     = a0;
        *(f32x4*)&red16[rowo][col8 * 8 + 4] = a1;
        __syncthreads();
        if (t < 128) {
            float s = 0.f;
            #pragma unroll
            for (int i = 0; i < 16; ++i) s += red16[i][t];
            cm[t] = s / (float)n;
        }
    }
    __syncthreads();

    // h = relu(colmean @ Wc1 + bc1)   (t = 0..255 -> d_h columns)
    float v = bc1[t];
    for (int i = 0; i < 128; ++i) v += cm[i] * Wc1[i * 256 + t];
    v = fmaxf(v, 0.f);

    // LN over 256
    red[t] = v; __syncthreads();
    for (int s = 128; s > 0; s >>= 1) { if (t < s) red[t] += red[t + s]; __syncthreads(); }
    float mu = red[0] * (1.f / 256.f);
    __syncthreads();
    red[t] = (v - mu) * (v - mu); __syncthreads();
    for (int s = 128; s > 0; s >>= 1) { if (t < s) red[t] += red[t + s]; __syncthreads(); }
    float var = red[0] * (1.f / 256.f);
    __syncthreads();
    hv[t] = (v - mu) * rsqrtf(var + 1e-5f) * g1[t] + be1[t];
    __syncthreads();

    // h2 = hv @ Wc2 + bc2  (t < 128)
    float v2 = 0.f;
    if (t < 128) {
        v2 = bc2[t];
        for (int i = 0; i < 256; ++i) v2 += hv[i] * Wc2[i * 128 + t];
    }
    __syncthreads();

    // LN over 128
    red[t] = (t < 128) ? v2 : 0.f; __syncthreads();
    for (int s = 128; s > 0; s >>= 1) { if (t < s) red[t] += red[t + s]; __syncthreads(); }
    mu = red[0] * (1.f / 128.f);
    __syncthreads();
    red[t] = (t < 128) ? (v2 - mu) * (v2 - mu) : 0.f; __syncthreads();
    for (int s = 128; s > 0; s >>= 1) { if (t < s) red[t] += red[t + s]; __syncthreads(); }
    var = red[0] * (1.f / 128.f);
    if (t < 128) gnn[t] = (v2 - mu) * rsqrtf(var + 1e-5f) * g2[t] + be2[t];
}

// ---------------------------------------------------------------------------
// Kernel C: fused 3-layer MLP, BM=64, 4 waves (N-split). bf16 MFMA, f32 acc.
// Weight fragments for layer L prefetched before the barrier preceding L,
// so the compiler's vmcnt(0) barrier-drain completes them during the barrier.
// ---------------------------------------------------------------------------
__global__ __launch_bounds__(256, 2) void k_main(
    const float* __restrict__ x,
    const float* __restrict__ bf1v, const float* __restrict__ bf2v,
    const float* __restrict__ bf3v,
    const u16* __restrict__ w1f, const u16* __restrict__ w2f,
    const u16* __restrict__ w3f,
    const float* __restrict__ gnn,
    float* __restrict__ out, int n)
{
    __shared__ __align__(16) u16 xs[64 * 128];
    __shared__ __align__(16) u16 h1[64 * 256];
    __shared__ __align__(16) u16 h2[64 * 256];

    int t = threadIdx.x;
    int row0 = blockIdx.x * 64;
    int w = t >> 6, lane = t & 63, lr = lane & 15, lq = lane >> 4;

    // ---- prefetch layer-1 weights + bias (pure global, completes by barrier)
    bf16x8 b1[4][4];
    {
        const bf16x8* base = (const bf16x8*)w1f;
        #pragma unroll
        for (int nt = 0; nt < 4; ++nt)
            #pragma unroll
            for (int k = 0; k < 4; ++k)
                b1[nt][k] = base[(((w * 4 + nt) * 4) + k) * 64 + lane];
    }
    float bias1[4];
    #pragma unroll
    for (int nt = 0; nt < 4; ++nt) bias1[nt] = bf1v[w * 64 + nt * 16 + lr];

    // ---- stage x tile -> xs (bf16, swizzled) ----
    #pragma unroll
    for (int it = 0; it < 4; ++it) {
        int G = t + it * 256;       // 1024 groups of 8
        int r = G >> 4, g = G & 15;
        int grow = row0 + r;
        f32x4 f0 = {0.f,0.f,0.f,0.f}, f1 = {0.f,0.f,0.f,0.f};
        if (grow < n) {
            const f32x4* p = (const f32x4*)(x + (long)grow * 128 + g * 8);
            f0 = p[0]; f1 = p[1];
        }
        *(bf16x8*)(&xs[r * 128 + ((g ^ (r & 7)) * 8)]) = pack8(f0, f1);
    }
    __syncthreads();

    // ---- layer 1: h1 = relu(x @ Wf1 + bf1), M=64 N=256 K=128 ----
    #pragma unroll
    for (int mt = 0; mt < 4; ++mt) {
        int arow = mt * 16 + lr;
        bf16x8 a[4];
        #pragma unroll
        for (int k = 0; k < 4; ++k) {
            int g = k * 4 + lq;
            a[k] = *(const bf16x8*)(&xs[arow * 128 + ((g ^ (arow & 7)) * 8)]);
        }
        #pragma unroll
        for (int nt = 0; nt < 4; ++nt) {
            f32x4 acc = {0.f,0.f,0.f,0.f};
            __builtin_amdgcn_s_setprio(1);
            #pragma unroll
            for (int k = 0; k < 4; ++k)
                acc = __builtin_amdgcn_mfma_f32_16x16x32_bf16(a[k], b1[nt][k], acc, 0, 0, 0);
            __builtin_amdgcn_s_setprio(0);
            int col = w * 64 + nt * 16 + lr;
            int cg = col >> 3, ce = col & 7;
            #pragma unroll
            for (int j = 0; j < 4; ++j) {
                int row = mt * 16 + lq * 4 + j;
                h1[row * 256 + ((cg ^ (row & 7)) * 8 + ce)] =
                    f2bf(fmaxf(acc[j] + bias1[nt], 0.f));
            }
        }
    }

    // ---- prefetch b2 half0 + bias2 before the barrier ----
    const bf16x8* base2 = (const bf16x8*)w2f;
    bf16x8 b2a[4][4];
    #pragma unroll
    for (int nt = 0; nt < 4; ++nt)
        #pragma unroll
        for (int k = 0; k < 4; ++k)
            b2a[nt][k] = base2[(((w * 4 + nt) * 8) + k) * 64 + lane];
    float bias2[4];
    #pragma unroll
    for (int nt = 0; nt < 4; ++nt) bias2[nt] = bf2v[w * 64 + nt * 16 + lr];
    __syncthreads();

    // ---- layer 2: h2 = relu(h1 @ Wf2 + bf2), M=64 N=256 K=256 ----
    {
        // issue half1 loads now; they complete under half0 compute
        bf16x8 b2b[4][4];
        #pragma unroll
        for (int nt = 0; nt < 4; ++nt)
            #pragma unroll
            for (int k = 0; k < 4; ++k)
                b2b[nt][k] = base2[(((w * 4 + nt) * 8) + 4 + k) * 64 + lane];

        f32x4 acc2[4][4];
        #pragma unroll
        for (int mt = 0; mt < 4; ++mt)
            #pragma unroll
            for (int nt = 0; nt < 4; ++nt)
                acc2[mt][nt] = (f32x4){0.f,0.f,0.f,0.f};

        #pragma unroll
        for (int mt = 0; mt < 4; ++mt) {          // half 0 (kk = 0..3)
            int arow = mt * 16 + lr;
            bf16x8 a[4];
            #pragma unroll
            for (int k = 0; k < 4; ++k) {
                int g = k * 4 + lq;
                a[k] = *(const bf16x8*)(&h1[arow * 256 + ((g ^ (arow & 7)) * 8)]);
            }
            __builtin_amdgcn_s_setprio(1);
            #pragma unroll
            for (int nt = 0; nt < 4; ++nt)
                #pragma unroll
                for (int k = 0; k < 4; ++k)
                    acc2[mt][nt] = __builtin_amdgcn_mfma_f32_16x16x32_bf16(a[k], b2a[nt][k], acc2[mt][nt], 0, 0, 0);
            __builtin_amdgcn_s_setprio(0);
        }
        #pragma unroll
        for (int mt = 0; mt < 4; ++mt) {          // half 1 (kk = 4..7)
            int arow = mt * 16 + lr;
            bf16x8 a[4];
            #pragma unroll
            for (int k = 0; k < 4; ++k) {
                int g = (4 + k) * 4 + lq;
                a[k] = *(const bf16x8*)(&h1[arow * 256 + ((g ^ (arow & 7)) * 8)]);
            }
            __builtin_amdgcn_s_setprio(1);
            #pragma unroll
            for (int nt = 0; nt < 4; ++nt)
                #pragma unroll
                for (int k = 0; k < 4; ++k)
                    acc2[mt][nt] = __builtin_amdgcn_mfma_f32_16x16x32_bf16(a[k], b2b[nt][k], acc2[mt][nt], 0, 0, 0);
            __builtin_amdgcn_s_setprio(0);
        }

        // ---- prefetch layer-3 weights + combined bias while acc2 -> h2 ----
        bf16x8 b3[2][8];
        {
            const bf16x8* base3 = (const bf16x8*)w3f;
            #pragma unroll
            for (int nt = 0; nt < 2; ++nt)
                #pragma unroll
                for (int k = 0; k < 8; ++k)
                    b3[nt][k] = base3[(((w * 2 + nt) * 8) + k) * 64 + lane];
        }
        float c3[2];
        #pragma unroll
        for (int nt = 0; nt < 2; ++nt) {
            int col = w * 32 + nt * 16 + lr;
            c3[nt] = bf3v[col] + gnn[col];
        }

        #pragma unroll
        for (int mt = 0; mt < 4; ++mt)
            #pragma unroll
            for (int nt = 0; nt < 4; ++nt) {
                int col = w * 64 + nt * 16 + lr;
                int cg = col >> 3, ce = col & 7;
                #pragma unroll
                for (int j = 0; j < 4; ++j) {
                    int row = mt * 16 + lq * 4 + j;
                    h2[row * 256 + ((cg ^ (row & 7)) * 8 + ce)] =
                        f2bf(fmaxf(acc2[mt][nt][j] + bias2[nt], 0.f));
                }
            }
        __syncthreads();

        // ---- layer 3: out = (h2 @ Wf3 + bf3 + gnn) * 0.5, M=64 N=128 K=256
        #pragma unroll
        for (int mt = 0; mt < 4; ++mt) {
            int arow = mt * 16 + lr;
            bf16x8 a[8];
            #pragma unroll
            for (int k = 0; k < 8; ++k) {
                int g = k * 4 + lq;
                a[k] = *(const bf16x8*)(&h2[arow * 256 + ((g ^ (arow & 7)) * 8)]);
            }
            #pragma unroll
            for (int nt = 0; nt < 2; ++nt) {
                f32x4 acc = {0.f,0.f,0.f,0.f};
                __builtin_amdgcn_s_setprio(1);
                #pragma unroll
                for (int k = 0; k < 8; ++k)
                    acc = __builtin_amdgcn_mfma_f32_16x16x32_bf16(a[k], b3[nt][k], acc, 0, 0, 0);
                __builtin_amdgcn_s_setprio(0);
                int col = w * 32 + nt * 16 + lr;
                #pragma unroll
                for (int j = 0; j < 4; ++j) {
                    int row = mt * 16 + lq * 4 + j;
                    int grow = row0 + row;
                    if (grow < n)
                        out[(long)grow * 128 + col] = (acc[j] + c3[nt]) * 0.5f;
                }
            }
        }
    }
}

extern "C" void kernel_launch(void* const* d_in, const int* in_sizes, int n_in,
                              void* d_out, int out_size, void* d_ws, size_t ws_size,
                              hipStream_t stream)
{
    const float* x   = (const float*)d_in[0];
    const float* Wc1 = (const float*)d_in[1];
    const float* bc1 = (const float*)d_in[2];
    const float* Wc2 = (const float*)d_in[3];
    const float* bc2 = (const float*)d_in[4];
    const float* g1  = (const float*)d_in[5];
    const float* be1 = (const float*)d_in[6];
    const float* g2  = (const float*)d_in[7];
    const float* be2 = (const float*)d_in[8];
    const float* Wf1 = (const float*)d_in[9];
    const float* b1  = (const float*)d_in[10];
    const float* Wf2 = (const float*)d_in[11];
    const float* b2  = (const float*)d_in[12];
    const float* Wf3 = (const float*)d_in[13];
    const float* b3  = (const float*)d_in[14];
    int n = in_sizes[0] / 128;

    char* ws = (char*)d_ws;
    float* gnn  = (float*)(ws + WS_GNN);
    u16*   w1f  = (u16*)(ws + WS_W1F);
    u16*   w2f  = (u16*)(ws + WS_W2F);
    u16*   w3f  = (u16*)(ws + WS_W3F);
    // colsum partials use d_out as scratch (k_main overwrites all of d_out
    // afterwards; same-stream ordering makes this deterministic).
    float* part = (float*)d_out;

    k_prep<<<CS_BLOCKS + 128, 256, 0, stream>>>(x, Wf1, Wf2, Wf3, part, w1f, w2f, w3f, n);
    k_gnn<<<1, 256, 0, stream>>>(part, Wc1, bc1, Wc2, bc2, g1, be1, g2, be2, gnn, n);
    int nb = (n + 63) / 64;
    k_main<<<nb, 256, 0, stream>>>(x, b1, b2, b3, w1f, w2f, w3f, gnn, (float*)d_out, n);
}

// Round 4
// 83.412 us; speedup vs baseline: 1.1828x; 1.1828x over previous
//
#include <hip/hip_runtime.h>
#include <hip/hip_bf16.h>

typedef float f32x4 __attribute__((ext_vector_type(4)));
typedef short bf16x8 __attribute__((ext_vector_type(8)));
typedef unsigned short u16;

#define CS_BLOCKS 512

// ws layout (bytes)
#define WS_PART 0         // 512 blocks * 128 f32 partial colsums = 262144 B
#define WS_GNN  262144    // 128 f32 = 512 B
#define WS_W1F  262656    // 64 frags * 1024 B = 65536
#define WS_W2F  328192    // 128 frags * 1024 B = 131072
#define WS_W3F  459264    // 64 frags * 1024 B = 65536  (end: 524800)

__device__ __forceinline__ u16 f2bf(float f) {
    __hip_bfloat16 h = __float2bfloat16(f);
    return *reinterpret_cast<u16*>(&h);
}

__device__ __forceinline__ bf16x8 pack8(f32x4 a, f32x4 b) {
    union { bf16x8 v; __hip_bfloat162 h[4]; } u;
    u.h[0] = __float22bfloat162_rn(make_float2(a[0], a[1]));
    u.h[1] = __float22bfloat162_rn(make_float2(a[2], a[3]));
    u.h[2] = __float22bfloat162_rn(make_float2(b[0], b[1]));
    u.h[3] = __float22bfloat162_rn(make_float2(b[2], b[3]));
    return u.v;
}

// ---------------------------------------------------------------------------
// Kernel A: blocks 0..CS_BLOCKS-1: per-block column-sum partials of x
//           (8 rows in flight, f32x4, unroll-4 => 4 loads outstanding).
//           blocks CS_BLOCKS..+127: repack Wf1/Wf2/Wf3 -> MFMA-frag bf16.
// ---------------------------------------------------------------------------
__global__ __launch_bounds__(256) void k_prep(
    const float* __restrict__ x,
    const float* __restrict__ Wf1, const float* __restrict__ Wf2,
    const float* __restrict__ Wf3,
    float* __restrict__ part, u16* __restrict__ w1f, u16* __restrict__ w2f,
    u16* __restrict__ w3f, int n)
{
    int b = blockIdx.x, t = threadIdx.x;
    if (b < CS_BLOCKS) {
        __shared__ float red8[8][128];
        int col4 = t & 31, rowo = t >> 5;       // col4: 16B chunk, rowo: 0..7
        int rpb = (n + CS_BLOCKS - 1) / CS_BLOCKS;
        int start = b * rpb;
        int end = min(start + rpb, n);
        f32x4 acc = {0.f, 0.f, 0.f, 0.f};
        #pragma unroll 4
        for (int r = start + rowo; r < end; r += 8)
            acc += *(const f32x4*)(x + (long)r * 128 + col4 * 4);
        *(f32x4*)&red8[rowo][col4 * 4] = acc;
        __syncthreads();
        if (t < 128) {
            float s = 0.f;
            #pragma unroll
            for (int i = 0; i < 8; ++i) s += red8[i][t];
            part[b * 128 + t] = s;
        }
    } else {
        int e0 = ((b - CS_BLOCKS) * 256 + t) * 4; // 131072 elems total
        #pragma unroll
        for (int i = 0; i < 4; ++i) {
            int e = e0 + i;
            u16* dst; const float* src; int KS, NW;
            if (e < 32768)      { dst = w1f; src = Wf1; KS = 4; NW = 256; }
            else if (e < 98304) { dst = w2f; src = Wf2; KS = 8; NW = 256; e -= 32768; }
            else                { dst = w3f; src = Wf3; KS = 8; NW = 128; e -= 98304; }
            int fi = e >> 9, within = e & 511;
            int lane = within >> 3, j = within & 7;
            int nt = fi / KS, k = fi - nt * KS;
            int nn = nt * 16 + (lane & 15);
            int kk = k * 32 + ((lane >> 4) & 3) * 8 + j;
            dst[fi * 512 + within] = f2bf(src[kk * NW + nn]);
        }
    }
}

// ---------------------------------------------------------------------------
// Kernel B: reduce colsum partials -> colmean, tiny GCN chain in f32.
// Shuffle-based block reductions; split-K matvec2; unroll-8 matvec loads.
// ---------------------------------------------------------------------------
__device__ __forceinline__ float block_sum(float v, float* wred, int t) {
    #pragma unroll
    for (int o = 32; o > 0; o >>= 1) v += __shfl_xor(v, o);
    if ((t & 63) == 0) wred[t >> 6] = v;
    __syncthreads();
    float s = wred[0] + wred[1] + wred[2] + wred[3];
    __syncthreads();
    return s;
}

__global__ __launch_bounds__(256) void k_gnn(
    const float* __restrict__ part,
    const float* __restrict__ Wc1, const float* __restrict__ bc1,
    const float* __restrict__ Wc2, const float* __restrict__ bc2,
    const float* __restrict__ g1,  const float* __restrict__ be1,
    const float* __restrict__ g2,  const float* __restrict__ be2,
    float* __restrict__ gnn, int n)
{
    int t = threadIdx.x;
    __shared__ float cm[128];
    __shared__ float hv[256];
    __shared__ float red[256];
    __shared__ float wred[4];
    __shared__ float red16[16][128];

    {   // vectorized partial reduce: CS_BLOCKS partials of 128 cols
        int col8 = t & 15, rowo = t >> 4;
        f32x4 a0 = {0.f,0.f,0.f,0.f}, a1 = {0.f,0.f,0.f,0.f};
        #pragma unroll 4
        for (int p = rowo; p < CS_BLOCKS; p += 16) {
            const f32x4* q = (const f32x4*)(part + p * 128 + col8 * 8);
            a0 += q[0]; a1 += q[1];
        }
        *(f32x4*)&red16[rowo][col8 * 8]     = a0;
        *(f32x4*)&red16[rowo][col8 * 8 + 4] = a1;
        __syncthreads();
        if (t < 128) {
            float s = 0.f;
            #pragma unroll
            for (int i = 0; i < 16; ++i) s += red16[i][t];
            cm[t] = s / (float)n;
        }
    }
    __syncthreads();

    // mv1: v = relu(cm @ Wc1 + bc1), 256 outputs, unroll-8 for load ILP
    float v = bc1[t];
    #pragma unroll 8
    for (int i = 0; i < 128; ++i) v += cm[i] * Wc1[i * 256 + t];
    v = fmaxf(v, 0.f);

    // LN over 256
    float mu = block_sum(v, wred, t) * (1.f / 256.f);
    float d = v - mu;
    float var = block_sum(d * d, wred, t) * (1.f / 256.f);
    hv[t] = d * rsqrtf(var + 1e-5f) * g1[t] + be1[t];
    __syncthreads();

    // mv2 split-K: col = t&127, half = t>>7, 128 iters each
    {
        int col = t & 127, half = t >> 7;
        float p = 0.f;
        #pragma unroll 8
        for (int i = half * 128; i < half * 128 + 128; ++i)
            p += hv[i] * Wc2[i * 128 + col];
        red[t] = p;
    }
    __syncthreads();
    float v2 = 0.f;
    bool lo = (t < 128);
    if (lo) v2 = bc2[t] + red[t] + red[t + 128];

    // LN over 128 (upper threads contribute 0)
    float mu2 = block_sum(lo ? v2 : 0.f, wred, t) * (1.f / 128.f);
    float d2 = v2 - mu2;
    float var2 = block_sum(lo ? d2 * d2 : 0.f, wred, t) * (1.f / 128.f);
    if (lo) gnn[t] = d2 * rsqrtf(var2 + 1e-5f) * g2[t] + be2[t];
}

// ---------------------------------------------------------------------------
// Kernel C: fused 3-layer MLP, BM=32, 4 waves (N-split), 40KB LDS =>
// 4 blocks/CU. bf16 MFMA, f32 accum. Weight loads chunked (2 k-frags at a
// time) so live set stays < 128 VGPR (no spill). XOR-swizzled LDS tiles.
// ---------------------------------------------------------------------------
__global__ __launch_bounds__(256, 4) void k_main(
    const float* __restrict__ x,
    const float* __restrict__ bf1v, const float* __restrict__ bf2v,
    const float* __restrict__ bf3v,
    const u16* __restrict__ w1f, const u16* __restrict__ w2f,
    const u16* __restrict__ w3f,
    const float* __restrict__ gnn,
    float* __restrict__ out, int n)
{
    __shared__ __align__(16) u16 xs[32 * 128];   // 8 KB
    __shared__ __align__(16) u16 h1[32 * 256];   // 16 KB
    __shared__ __align__(16) u16 h2[32 * 256];   // 16 KB

    int t = threadIdx.x;
    int row0 = blockIdx.x * 32;
    int w = t >> 6, lane = t & 63, lr = lane & 15, lq = lane >> 4;

    // ---- stage x tile -> xs (bf16, swizzled): 512 groups of 8 ----
    #pragma unroll
    for (int it = 0; it < 2; ++it) {
        int G = t + it * 256;
        int r = G >> 4, g = G & 15;
        int grow = row0 + r;
        f32x4 f0 = {0.f,0.f,0.f,0.f}, f1 = {0.f,0.f,0.f,0.f};
        if (grow < n) {
            const f32x4* p = (const f32x4*)(x + (long)grow * 128 + g * 8);
            f0 = p[0]; f1 = p[1];
        }
        *(bf16x8*)(&xs[r * 128 + ((g ^ (r & 7)) * 8)]) = pack8(f0, f1);
    }
    __syncthreads();

    // ---- layer 1: h1 = relu(x @ Wf1 + bf1), M=32 N=256 K=128 ----
    {
        bf16x8 b1[4][4];
        const bf16x8* base = (const bf16x8*)w1f;
        #pragma unroll
        for (int nt = 0; nt < 4; ++nt)
            #pragma unroll
            for (int k = 0; k < 4; ++k)
                b1[nt][k] = base[(((w * 4 + nt) * 4) + k) * 64 + lane];
        float bias1[4];
        #pragma unroll
        for (int nt = 0; nt < 4; ++nt) bias1[nt] = bf1v[w * 64 + nt * 16 + lr];

        #pragma unroll
        for (int mt = 0; mt < 2; ++mt) {
            int arow = mt * 16 + lr;
            bf16x8 a[4];
            #pragma unroll
            for (int k = 0; k < 4; ++k) {
                int g = k * 4 + lq;
                a[k] = *(const bf16x8*)(&xs[arow * 128 + ((g ^ (arow & 7)) * 8)]);
            }
            #pragma unroll
            for (int nt = 0; nt < 4; ++nt) {
                f32x4 acc = {0.f,0.f,0.f,0.f};
                #pragma unroll
                for (int k = 0; k < 4; ++k)
                    acc = __builtin_amdgcn_mfma_f32_16x16x32_bf16(a[k], b1[nt][k], acc, 0, 0, 0);
                int col = w * 64 + nt * 16 + lr;
                int cg = col >> 3, ce = col & 7;
                #pragma unroll
                for (int j = 0; j < 4; ++j) {
                    int row = mt * 16 + lq * 4 + j;
                    h1[row * 256 + ((cg ^ (row & 7)) * 8 + ce)] =
                        f2bf(fmaxf(acc[j] + bias1[nt], 0.f));
                }
            }
        }
    }
    __syncthreads();

    // ---- layer 2: h2 = relu(h1 @ Wf2 + bf2), M=32 N=256 K=256 ----
    {
        f32x4 acc2[2][4];
        #pragma unroll
        for (int mt = 0; mt < 2; ++mt)
            #pragma unroll
            for (int nt = 0; nt < 4; ++nt)
                acc2[mt][nt] = (f32x4){0.f,0.f,0.f,0.f};

        const bf16x8* base = (const bf16x8*)w2f;
        #pragma unroll
        for (int kb = 0; kb < 4; ++kb) {        // 2 k-frags per chunk
            bf16x8 bc[4][2];
            #pragma unroll
            for (int nt = 0; nt < 4; ++nt)
                #pragma unroll
                for (int k = 0; k < 2; ++k)
                    bc[nt][k] = base[(((w * 4 + nt) * 8) + kb * 2 + k) * 64 + lane];
            #pragma unroll
            for (int mt = 0; mt < 2; ++mt) {
                int arow = mt * 16 + lr;
                bf16x8 a[2];
                #pragma unroll
                for (int k = 0; k < 2; ++k) {
                    int g = (kb * 2 + k) * 4 + lq;
                    a[k] = *(const bf16x8*)(&h1[arow * 256 + ((g ^ (arow & 7)) * 8)]);
                }
                #pragma unroll
                for (int nt = 0; nt < 4; ++nt)
                    #pragma unroll
                    for (int k = 0; k < 2; ++k)
                        acc2[mt][nt] = __builtin_amdgcn_mfma_f32_16x16x32_bf16(a[k], bc[nt][k], acc2[mt][nt], 0, 0, 0);
            }
        }

        float bias2[4];
        #pragma unroll
        for (int nt = 0; nt < 4; ++nt) bias2[nt] = bf2v[w * 64 + nt * 16 + lr];

        #pragma unroll
        for (int mt = 0; mt < 2; ++mt)
            #pragma unroll
            for (int nt = 0; nt < 4; ++nt) {
                int col = w * 64 + nt * 16 + lr;
                int cg = col >> 3, ce = col & 7;
                #pragma unroll
                for (int j = 0; j < 4; ++j) {
                    int row = mt * 16 + lq * 4 + j;
                    h2[row * 256 + ((cg ^ (row & 7)) * 8 + ce)] =
                        f2bf(fmaxf(acc2[mt][nt][j] + bias2[nt], 0.f));
                }
            }
    }
    __syncthreads();

    // ---- layer 3: out = (h2 @ Wf3 + bf3 + gnn) * 0.5, M=32 N=128 K=256 ----
    {
        f32x4 acc3[2][2];
        #pragma unroll
        for (int mt = 0; mt < 2; ++mt)
            #pragma unroll
            for (int nt = 0; nt < 2; ++nt)
                acc3[mt][nt] = (f32x4){0.f,0.f,0.f,0.f};

        const bf16x8* base = (const bf16x8*)w3f;
        #pragma unroll
        for (int kb = 0; kb < 4; ++kb) {
            bf16x8 bc[2][2];
            #pragma unroll
            for (int nt = 0; nt < 2; ++nt)
                #pragma unroll
                for (int k = 0; k < 2; ++k)
                    bc[nt][k] = base[(((w * 2 + nt) * 8) + kb * 2 + k) * 64 + lane];
            #pragma unroll
            for (int mt = 0; mt < 2; ++mt) {
                int arow = mt * 16 + lr;
                bf16x8 a[2];
                #pragma unroll
                for (int k = 0; k < 2; ++k) {
                    int g = (kb * 2 + k) * 4 + lq;
                    a[k] = *(const bf16x8*)(&h2[arow * 256 + ((g ^ (arow & 7)) * 8)]);
                }
                #pragma unroll
                for (int nt = 0; nt < 2; ++nt)
                    #pragma unroll
                    for (int k = 0; k < 2; ++k)
                        acc3[mt][nt] = __builtin_amdgcn_mfma_f32_16x16x32_bf16(a[k], bc[nt][k], acc3[mt][nt], 0, 0, 0);
            }
        }

        float c3[2];
        #pragma unroll
        for (int nt = 0; nt < 2; ++nt) {
            int col = w * 32 + nt * 16 + lr;
            c3[nt] = bf3v[col] + gnn[col];
        }
        #pragma unroll
        for (int mt = 0; mt < 2; ++mt)
            #pragma unroll
            for (int nt = 0; nt < 2; ++nt) {
                int col = w * 32 + nt * 16 + lr;
                #pragma unroll
                for (int j = 0; j < 4; ++j) {
                    int row = mt * 16 + lq * 4 + j;
                    int grow = row0 + row;
                    if (grow < n)
                        out[(long)grow * 128 + col] = (acc3[mt][nt][j] + c3[nt]) * 0.5f;
                }
            }
    }
}

extern "C" void kernel_launch(void* const* d_in, const int* in_sizes, int n_in,
                              void* d_out, int out_size, void* d_ws, size_t ws_size,
                              hipStream_t stream)
{
    const float* x   = (const float*)d_in[0];
    const float* Wc1 = (const float*)d_in[1];
    const float* bc1 = (const float*)d_in[2];
    const float* Wc2 = (const float*)d_in[3];
    const float* bc2 = (const float*)d_in[4];
    const float* g1  = (const float*)d_in[5];
    const float* be1 = (const float*)d_in[6];
    const float* g2  = (const float*)d_in[7];
    const float* be2 = (const float*)d_in[8];
    const float* Wf1 = (const float*)d_in[9];
    const float* b1  = (const float*)d_in[10];
    const float* Wf2 = (const float*)d_in[11];
    const float* b2  = (const float*)d_in[12];
    const float* Wf3 = (const float*)d_in[13];
    const float* b3  = (const float*)d_in[14];
    int n = in_sizes[0] / 128;

    char* ws = (char*)d_ws;
    float* part = (float*)(ws + WS_PART);
    float* gnn  = (float*)(ws + WS_GNN);
    u16*   w1f  = (u16*)(ws + WS_W1F);
    u16*   w2f  = (u16*)(ws + WS_W2F);
    u16*   w3f  = (u16*)(ws + WS_W3F);

    k_prep<<<CS_BLOCKS + 128, 256, 0, stream>>>(x, Wf1, Wf2, Wf3, part, w1f, w2f, w3f, n);
    k_gnn<<<1, 256, 0, stream>>>(part, Wc1, bc1, Wc2, bc2, g1, be1, g2, be2, gnn, n);
    int nb = (n + 31) / 32;
    k_main<<<nb, 256, 0, stream>>>(x, b1, b2, b3, w1f, w2f, w3f, gnn, (float*)d_out, n);
}